// Round 1
// baseline (2027.538 us; speedup 1.0000x reference)
//
#include <hip/hip_runtime.h>
#include <hip/hip_bf16.h>

typedef __attribute__((ext_vector_type(8))) short bf16x8;
typedef __attribute__((ext_vector_type(4))) float f32x4;

#define BM 128
#define BN 128
#define BK 64
#define LDK 72   // padded LDS K-stride (bf16 elems) -> 144 B row stride

__device__ __forceinline__ float bf2f(unsigned short u) {
    union { unsigned int i; float f; } v; v.i = ((unsigned int)u) << 16; return v.f;
}
__device__ __forceinline__ unsigned short f2bf(float f) {
    union { float f; unsigned int i; } v; v.f = f;
    unsigned int x = v.i;
    return (unsigned short)((x + 0x7FFFu + ((x >> 16) & 1u)) >> 16);
}

// ---------------------------------------------------------------------------
// concat(motion, command) -> bf16 [8192, 576]
// ---------------------------------------------------------------------------
__global__ void concat_cvt(const float* __restrict__ motion,
                           const float* __restrict__ command,
                           unsigned short* __restrict__ out) {
    int id = blockIdx.x * 256 + threadIdx.x;      // 8192*144 quads
    int b = id / 144, q = id % 144;
    float4 v;
    if (q < 128) v = *(const float4*)(motion + (size_t)b * 512 + q * 4);
    else         v = *(const float4*)(command + (size_t)b * 64 + (q - 128) * 4);
    ushort4 o;
    o.x = f2bf(v.x); o.y = f2bf(v.y); o.z = f2bf(v.z); o.w = f2bf(v.w);
    *(ushort4*)(out + (size_t)b * 576 + q * 4) = o;
}

// ---------------------------------------------------------------------------
// fp32 [K,N] -> bf16 [N,K]  (weight transpose + convert), 64x64 tiles
// ---------------------------------------------------------------------------
__global__ void transpose_cvt(const float* __restrict__ in,
                              unsigned short* __restrict__ out,
                              int K, int N) {
    __shared__ unsigned short tile[64][72];
    int nbn = N / 64;
    int k0 = (blockIdx.x / nbn) * 64;
    int n0 = (blockIdx.x % nbn) * 64;
    int t = threadIdx.x;
    int tx = t & 63, ty = t >> 6;                 // ty 0..3
    #pragma unroll
    for (int rr = 0; rr < 16; ++rr) {
        int kr = ty + rr * 4;
        tile[kr][tx] = f2bf(in[(size_t)(k0 + kr) * N + n0 + tx]);
    }
    __syncthreads();
    int txh = t & 31, tyh = t >> 5;               // tyh 0..7
    #pragma unroll
    for (int rr = 0; rr < 8; ++rr) {
        int nr = tyh + rr * 8;
        unsigned int vlo = tile[2 * txh][nr];
        unsigned int vhi = tile[2 * txh + 1][nr];
        unsigned int* o32 = (unsigned int*)(out + (size_t)(n0 + nr) * K + k0);
        o32[txh] = vlo | (vhi << 16);
    }
}

// ---------------------------------------------------------------------------
// gating final: coeffs = softmax(g2 @ w3 + b3), g2 bf16 [8192,1024], w3 f32 [1024,8]
// ---------------------------------------------------------------------------
__global__ __launch_bounds__(256) void gating_kernel(
    const unsigned short* __restrict__ g2,
    const float* __restrict__ w3, const float* __restrict__ b3,
    float* __restrict__ coeffs) {
    __shared__ float w3s[8][1024];
    int t = threadIdx.x;
    for (int i = t; i < 1024; i += 256) {
        #pragma unroll
        for (int e = 0; e < 8; ++e) w3s[e][i] = w3[(size_t)i * 8 + e];
    }
    __syncthreads();
    int lane = t & 63, wv = t >> 6;
    int row = blockIdx.x * 4 + wv;
    const unsigned short* xr = g2 + (size_t)row * 1024;
    float acc[8];
    #pragma unroll
    for (int e = 0; e < 8; ++e) acc[e] = 0.f;
    for (int it = 0; it < 16; ++it) {
        float xv = bf2f(xr[lane + it * 64]);
        #pragma unroll
        for (int e = 0; e < 8; ++e) acc[e] += xv * w3s[e][lane + it * 64];
    }
    #pragma unroll
    for (int e = 0; e < 8; ++e) {
        float v = acc[e];
        #pragma unroll
        for (int off = 32; off; off >>= 1) v += __shfl_xor(v, off);
        acc[e] = v + b3[e];
    }
    float mx = acc[0];
    #pragma unroll
    for (int e = 1; e < 8; ++e) mx = fmaxf(mx, acc[e]);
    float s = 0.f;
    #pragma unroll
    for (int e = 0; e < 8; ++e) { acc[e] = __expf(acc[e] - mx); s += acc[e]; }
    float inv = 1.f / s;
    if (lane < 8) coeffs[(size_t)row * 8 + lane] = acc[lane] * inv;
}

// ---------------------------------------------------------------------------
// GEMM: Out[M,N] = act( A' @ WT^T + bias ),  WT is [N,K] bf16 row-major.
// MOE: A'[b, e*din+i] = coeffs[b,e] * X[b,i]   (X row stride = din)
// else: A' = X, K == din.
// ---------------------------------------------------------------------------
template<bool MOE, bool DO_ELU, bool OUT_F32>
__global__ __launch_bounds__(256, 2)
void gemm_kernel(const unsigned short* __restrict__ X,
                 const unsigned short* __restrict__ WT,
                 const float* __restrict__ coeffs,
                 const float* __restrict__ bias,
                 void* __restrict__ Out,
                 int M, int N, int K, int din) {
    __shared__ unsigned short As[BM * LDK];
    __shared__ unsigned short Bs[BN * LDK];

    int nTilesN = N / BN;
    int nwg = gridDim.x;
    int bid = blockIdx.x;
    if ((nwg & 7) == 0) {                         // XCD-chunked swizzle
        int cpx = nwg >> 3;
        bid = (bid & 7) * cpx + (bid >> 3);
    }
    int tm = bid / nTilesN, tn = bid % nTilesN;
    int row0 = tm * BM, col0 = tn * BN;

    int t = threadIdx.x;
    int lane = t & 63;
    int wid = t >> 6;
    int wr = wid >> 1, wc = wid & 1;              // 2x2 waves, 64x64 each

    int srow = t >> 1;                            // staging row 0..127
    int sslot = (t & 1) * 4;                      // 16B slots 0-3 / 4-7

    const unsigned short* Xrow = X + (size_t)(row0 + srow) * din;
    const unsigned short* Wrow = WT + (size_t)(col0 + srow) * K;

    f32x4 acc[4][4];
    #pragma unroll
    for (int i = 0; i < 4; ++i)
        #pragma unroll
        for (int j = 0; j < 4; ++j) acc[i][j] = (f32x4){0.f, 0.f, 0.f, 0.f};

    uint4 ra[4], rb[4];
    float scale = 1.0f;
    int nkt = K / BK;

    auto load_tile = [&](int kt) {
        int i0 = kt * BK;
        if (MOE) {
            int e = (kt * BK) / din;
            i0 = kt * BK - e * din;
            scale = coeffs[(size_t)(row0 + srow) * 8 + e];
        }
        #pragma unroll
        for (int q = 0; q < 4; ++q) {
            ra[q] = *(const uint4*)(Xrow + i0 + (sslot + q) * 8);
            rb[q] = *(const uint4*)(Wrow + kt * BK + (sslot + q) * 8);
        }
    };

    auto store_tile = [&]() {
        #pragma unroll
        for (int q = 0; q < 4; ++q) {
            uint4 v = ra[q];
            if (MOE) {
                unsigned int w[4] = {v.x, v.y, v.z, v.w};
                #pragma unroll
                for (int p = 0; p < 4; ++p) {
                    float lo = bf2f((unsigned short)(w[p] & 0xFFFFu)) * scale;
                    float hi = bf2f((unsigned short)(w[p] >> 16)) * scale;
                    w[p] = (unsigned int)f2bf(lo) | ((unsigned int)f2bf(hi) << 16);
                }
                v.x = w[0]; v.y = w[1]; v.z = w[2]; v.w = w[3];
            }
            *(uint4*)(&As[srow * LDK + (sslot + q) * 8]) = v;
            *(uint4*)(&Bs[srow * LDK + (sslot + q) * 8]) = rb[q];
        }
    };

    load_tile(0);
    for (int kt = 0; kt < nkt; ++kt) {
        store_tile();
        __syncthreads();
        if (kt + 1 < nkt) load_tile(kt + 1);
        #pragma unroll
        for (int kk = 0; kk < 2; ++kk) {
            bf16x8 af[4], bfr[4];
            #pragma unroll
            for (int m = 0; m < 4; ++m)
                af[m] = *(const bf16x8*)(&As[(wr * 64 + m * 16 + (lane & 15)) * LDK + kk * 32 + (lane >> 4) * 8]);
            #pragma unroll
            for (int n = 0; n < 4; ++n)
                bfr[n] = *(const bf16x8*)(&Bs[(wc * 64 + n * 16 + (lane & 15)) * LDK + kk * 32 + (lane >> 4) * 8]);
            #pragma unroll
            for (int m = 0; m < 4; ++m)
                #pragma unroll
                for (int n = 0; n < 4; ++n)
                    acc[m][n] = __builtin_amdgcn_mfma_f32_16x16x32_bf16(af[m], bfr[n], acc[m][n], 0, 0, 0);
        }
        __syncthreads();
    }

    // epilogue: bias (+MoE mix), activation, store
    #pragma unroll
    for (int m = 0; m < 4; ++m) {
        int rbase = row0 + wr * 64 + m * 16 + ((lane >> 4) << 2);
        float crow[4][8];
        if (MOE) {
            #pragma unroll
            for (int r = 0; r < 4; ++r) {
                const float* cp = coeffs + (size_t)(rbase + r) * 8;
                #pragma unroll
                for (int e = 0; e < 8; ++e) crow[r][e] = cp[e];
            }
        }
        #pragma unroll
        for (int n = 0; n < 4; ++n) {
            int cg = col0 + wc * 64 + n * 16 + (lane & 15);
            float bv[8];
            if (MOE) {
                #pragma unroll
                for (int e = 0; e < 8; ++e) bv[e] = bias[(size_t)e * N + cg];
            } else {
                bv[0] = bias[cg];
            }
            #pragma unroll
            for (int r = 0; r < 4; ++r) {
                float v = acc[m][n][r];
                if (MOE) {
                    #pragma unroll
                    for (int e = 0; e < 8; ++e) v += crow[r][e] * bv[e];
                } else {
                    v += bv[0];
                }
                if (DO_ELU) v = v > 0.f ? v : (__expf(v) - 1.f);
                int rg = rbase + r;
                if (OUT_F32) ((float*)Out)[(size_t)rg * N + cg] = v;
                else ((unsigned short*)Out)[(size_t)rg * N + cg] = f2bf(v);
            }
        }
    }
}

// ---------------------------------------------------------------------------
extern "C" void kernel_launch(void* const* d_in, const int* in_sizes, int n_in,
                              void* d_out, int out_size, void* d_ws, size_t ws_size,
                              hipStream_t stream) {
    const float* motion  = (const float*)d_in[0];
    const float* command = (const float*)d_in[1];
    const float* g_w1 = (const float*)d_in[2];
    const float* g_b1 = (const float*)d_in[3];
    const float* g_w2 = (const float*)d_in[4];
    const float* g_b2 = (const float*)d_in[5];
    const float* g_w3 = (const float*)d_in[6];
    const float* g_b3 = (const float*)d_in[7];
    const float* w[6]  = {(const float*)d_in[8],  (const float*)d_in[10],
                          (const float*)d_in[12], (const float*)d_in[14],
                          (const float*)d_in[16], (const float*)d_in[18]};
    const float* bb[6] = {(const float*)d_in[9],  (const float*)d_in[11],
                          (const float*)d_in[13], (const float*)d_in[15],
                          (const float*)d_in[17], (const float*)d_in[19]};

    char* ws = (char*)d_ws;
    unsigned short* xc0  = (unsigned short*)ws;                        //  9,437,184 B
    unsigned short* actA = (unsigned short*)(ws + 9437184);            // 16,777,216 B
    unsigned short* actB = (unsigned short*)(ws + 9437184 + 16777216); // 16,777,216 B
    float* coeffs        = (float*)(ws + 9437184 + 2 * 16777216);      //    262,144 B
    unsigned short* wT   = (unsigned short*)(ws + 9437184 + 2 * 16777216 + 262144); // 16,777,216 B

    // 1. concat + convert input
    concat_cvt<<<4608, 256, 0, stream>>>(motion, command, xc0);

    // 2. gating layer 1: [8192,576]x[576,1024], ELU
    transpose_cvt<<<(576 / 64) * (1024 / 64), 256, 0, stream>>>(g_w1, wT, 576, 1024);
    gemm_kernel<false, true, false><<<64 * 8, 256, 0, stream>>>(
        xc0, wT, nullptr, g_b1, actA, 8192, 1024, 576, 576);

    // 3. gating layer 2: [8192,1024]x[1024,1024], ELU
    transpose_cvt<<<(1024 / 64) * (1024 / 64), 256, 0, stream>>>(g_w2, wT, 1024, 1024);
    gemm_kernel<false, true, false><<<64 * 8, 256, 0, stream>>>(
        actA, wT, nullptr, g_b2, actB, 8192, 1024, 1024, 1024);

    // 4. gating head + softmax -> coeffs [8192,8]
    gating_kernel<<<2048, 256, 0, stream>>>(actB, g_w3, g_b3, coeffs);

    // 5. MoE layer 0: K = 8*576 = 4608, din=576, in xc0 -> actA
    transpose_cvt<<<(4608 / 64) * (1024 / 64), 256, 0, stream>>>(w[0], wT, 4608, 1024);
    gemm_kernel<true, true, false><<<64 * 8, 256, 0, stream>>>(
        xc0, wT, coeffs, bb[0], actA, 8192, 1024, 4608, 576);

    // 6. MoE layers 1..4: K = 8192, din=1024, ping-pong actA/actB
    unsigned short* bufs[2] = {actA, actB};
    for (int l = 1; l <= 4; ++l) {
        transpose_cvt<<<(8192 / 64) * (1024 / 64), 256, 0, stream>>>(w[l], wT, 8192, 1024);
        gemm_kernel<true, true, false><<<64 * 8, 256, 0, stream>>>(
            bufs[(l + 1) & 1], wT, coeffs, bb[l], bufs[l & 1], 8192, 1024, 8192, 1024);
    }

    // 7. MoE layer 5: K=8192, N=512, no ELU, fp32 out -> d_out
    transpose_cvt<<<(8192 / 64) * (512 / 64), 256, 0, stream>>>(w[5], wT, 8192, 512);
    gemm_kernel<true, false, true><<<64 * 4, 256, 0, stream>>>(
        actA, wT, coeffs, bb[5], (float*)d_out, 8192, 512, 8192, 1024);
}

// Round 2
// 1161.041 us; speedup vs baseline: 1.7463x; 1.7463x over previous
//
#include <hip/hip_runtime.h>
#include <hip/hip_bf16.h>

typedef __attribute__((ext_vector_type(8))) short bf16x8;
typedef __attribute__((ext_vector_type(4))) float f32x4;

__device__ __forceinline__ float bf2f(unsigned short u) {
    union { unsigned int i; float f; } v; v.i = ((unsigned int)u) << 16; return v.f;
}
__device__ __forceinline__ unsigned short f2bf(float f) {
    union { float f; unsigned int i; } v; v.f = f;
    unsigned int x = v.i;
    return (unsigned short)((x + 0x7FFFu + ((x >> 16) & 1u)) >> 16);
}

__device__ __forceinline__ void gload_lds16(const unsigned short* g, unsigned short* l) {
    __builtin_amdgcn_global_load_lds(
        (const __attribute__((address_space(1))) unsigned int*)g,
        (__attribute__((address_space(3))) unsigned int*)l,
        16, 0, 0);
}

// ---------------------------------------------------------------------------
// concat(motion, command) -> bf16 [8192, 576]
// ---------------------------------------------------------------------------
__global__ void concat_cvt(const float* __restrict__ motion,
                           const float* __restrict__ command,
                           unsigned short* __restrict__ out) {
    int id = blockIdx.x * 256 + threadIdx.x;      // 8192*144 quads
    int b = id / 144, q = id % 144;
    float4 v;
    if (q < 128) v = *(const float4*)(motion + (size_t)b * 512 + q * 4);
    else         v = *(const float4*)(command + (size_t)b * 64 + (q - 128) * 4);
    ushort4 o;
    o.x = f2bf(v.x); o.y = f2bf(v.y); o.z = f2bf(v.z); o.w = f2bf(v.w);
    *(ushort4*)(out + (size_t)b * 576 + q * 4) = o;
}

// ---------------------------------------------------------------------------
// fp32 [K,N] -> bf16 [N,K]  (weight transpose + convert), 64x64 tiles
// ---------------------------------------------------------------------------
__global__ void transpose_cvt(const float* __restrict__ in,
                              unsigned short* __restrict__ out,
                              int K, int N) {
    __shared__ unsigned short tile[64][72];
    int nbn = N / 64;
    int k0 = (blockIdx.x / nbn) * 64;
    int n0 = (blockIdx.x % nbn) * 64;
    int t = threadIdx.x;
    int tx = t & 63, ty = t >> 6;                 // ty 0..3
    #pragma unroll
    for (int rr = 0; rr < 16; ++rr) {
        int kr = ty + rr * 4;
        tile[kr][tx] = f2bf(in[(size_t)(k0 + kr) * N + n0 + tx]);
    }
    __syncthreads();
    int txh = t & 31, tyh = t >> 5;               // tyh 0..7
    #pragma unroll
    for (int rr = 0; rr < 8; ++rr) {
        int nr = tyh + rr * 8;
        unsigned int vlo = tile[2 * txh][nr];
        unsigned int vhi = tile[2 * txh + 1][nr];
        unsigned int* o32 = (unsigned int*)(out + (size_t)(n0 + nr) * K + k0);
        o32[txh] = vlo | (vhi << 16);
    }
}

// ---------------------------------------------------------------------------
// gating final: coeffs = softmax(g2 @ w3 + b3)
// ---------------------------------------------------------------------------
__global__ __launch_bounds__(256) void gating_kernel(
    const unsigned short* __restrict__ g2,
    const float* __restrict__ w3, const float* __restrict__ b3,
    float* __restrict__ coeffs) {
    __shared__ float w3s[8][1024];
    int t = threadIdx.x;
    for (int i = t; i < 1024; i += 256) {
        #pragma unroll
        for (int e = 0; e < 8; ++e) w3s[e][i] = w3[(size_t)i * 8 + e];
    }
    __syncthreads();
    int lane = t & 63, wv = t >> 6;
    int row = blockIdx.x * 4 + wv;
    const unsigned short* xr = g2 + (size_t)row * 1024;
    float acc[8];
    #pragma unroll
    for (int e = 0; e < 8; ++e) acc[e] = 0.f;
    for (int it = 0; it < 16; ++it) {
        float xv = bf2f(xr[lane + it * 64]);
        #pragma unroll
        for (int e = 0; e < 8; ++e) acc[e] += xv * w3s[e][lane + it * 64];
    }
    #pragma unroll
    for (int e = 0; e < 8; ++e) {
        float v = acc[e];
        #pragma unroll
        for (int off = 32; off; off >>= 1) v += __shfl_xor(v, off);
        acc[e] = v + b3[e];
    }
    float mx = acc[0];
    #pragma unroll
    for (int e = 1; e < 8; ++e) mx = fmaxf(mx, acc[e]);
    float s = 0.f;
    #pragma unroll
    for (int e = 0; e < 8; ++e) { acc[e] = __expf(acc[e] - mx); s += acc[e]; }
    float inv = 1.f / s;
    if (lane < 8) coeffs[(size_t)row * 8 + lane] = acc[lane] * inv;
}

// ---------------------------------------------------------------------------
// expand: A'[b, e*din+i] = coeffs[b,e] * X[b,i]   (bf16)
// ---------------------------------------------------------------------------
__global__ void expand_scale(const unsigned short* __restrict__ X,
                             const float* __restrict__ coeffs,
                             unsigned short* __restrict__ A, int din) {
    int id = blockIdx.x * 256 + threadIdx.x;      // 8192 * din chunks of 8
    int cpr = din;                                // 8*din/8 chunks per out row
    int b = id / cpr, kc = id % cpr;
    int cpe = din >> 3;                           // chunks per expert
    int e = kc / cpe;
    int ic = kc - e * cpe;
    float c = coeffs[(size_t)b * 8 + e];
    uint4 v = *(const uint4*)(X + (size_t)b * din + ic * 8);
    unsigned int w[4] = {v.x, v.y, v.z, v.w};
    #pragma unroll
    for (int p = 0; p < 4; ++p) {
        float lo = bf2f((unsigned short)(w[p] & 0xFFFFu)) * c;
        float hi = bf2f((unsigned short)(w[p] >> 16)) * c;
        w[p] = (unsigned int)f2bf(lo) | ((unsigned int)f2bf(hi) << 16);
    }
    uint4 o; o.x = w[0]; o.y = w[1]; o.z = w[2]; o.w = w[3];
    *(uint4*)(A + (size_t)b * 8 * din + (size_t)kc * 8) = o;
}

// ---------------------------------------------------------------------------
// split-K reduce: out = act( sum_s P_s + sum_e c_e * bias_e )
// ---------------------------------------------------------------------------
template<int SPLITS, bool DO_ELU, bool OUT_F32>
__global__ void reduce_bias(const float* __restrict__ P,
                            const float* __restrict__ coeffs,
                            const float* __restrict__ bias,   // [8, N]
                            void* __restrict__ Out, int N) {
    int id = blockIdx.x * 256 + threadIdx.x;      // 8192*N/4
    int nc = N >> 2;
    int b = id / nc, oc = id % nc;
    float4 s = {0.f, 0.f, 0.f, 0.f};
    #pragma unroll
    for (int sp = 0; sp < SPLITS; ++sp) {
        float4 p = *(const float4*)(P + (size_t)sp * 8192 * N + (size_t)b * N + oc * 4);
        s.x += p.x; s.y += p.y; s.z += p.z; s.w += p.w;
    }
    const float* c = coeffs + (size_t)b * 8;
    #pragma unroll
    for (int e = 0; e < 8; ++e) {
        float ce = c[e];
        float4 bv = *(const float4*)(bias + (size_t)e * N + oc * 4);
        s.x += ce * bv.x; s.y += ce * bv.y; s.z += ce * bv.z; s.w += ce * bv.w;
    }
    if (DO_ELU) {
        s.x = s.x > 0.f ? s.x : (__expf(s.x) - 1.f);
        s.y = s.y > 0.f ? s.y : (__expf(s.y) - 1.f);
        s.z = s.z > 0.f ? s.z : (__expf(s.z) - 1.f);
        s.w = s.w > 0.f ? s.w : (__expf(s.w) - 1.f);
    }
    if (OUT_F32) {
        *(float4*)((float*)Out + (size_t)b * N + oc * 4) = s;
    } else {
        ushort4 o;
        o.x = f2bf(s.x); o.y = f2bf(s.y); o.z = f2bf(s.z); o.w = f2bf(s.w);
        *(ushort4*)((unsigned short*)Out + (size_t)b * N + oc * 4) = o;
    }
}

// ---------------------------------------------------------------------------
// pure bf16 GEMM, m97 structure: 128x128x64 tile, linear LDS, global_load_lds.
// A [8192, ld] (use k-range [k0, k0+kpart)), BT [N, ld].
// MODE 0: fused bias+optional-ELU, bf16 out [8192,N].
// MODE 1: fp32 partial out at P + s*8192*N.
// ---------------------------------------------------------------------------
template<int MODE, bool DO_ELU>
__global__ __launch_bounds__(256, 4)
void gemm_bf16(const unsigned short* __restrict__ A,
               const unsigned short* __restrict__ BT,
               const float* __restrict__ bias,
               void* __restrict__ Out,
               int N, int ld, int kpart) {
    __shared__ unsigned short As[128 * 64];
    __shared__ unsigned short Bs[128 * 64];

    int ntn = N >> 7;
    int nwg = gridDim.x;
    int bid = blockIdx.x;
    { int cpx = nwg >> 3; bid = (bid & 7) * cpx + (bid >> 3); }  // XCD swizzle
    int tiles = 64 * ntn;
    int s = bid / tiles;
    int r = bid - s * tiles;
    int tm = r / ntn, tn = r - tm * ntn;
    int row0 = tm << 7, col0 = tn << 7;
    int k0 = s * kpart;

    int t = threadIdx.x;
    int lane = t & 63;
    int wid = t >> 6;
    int wr = wid >> 1, wc = wid & 1;

    const unsigned short* Ab = A + (size_t)(row0 + wid * 32 + (lane >> 3)) * ld + k0 + (lane & 7) * 8;
    const unsigned short* Bb = BT + (size_t)(col0 + wid * 32 + (lane >> 3)) * ld + k0 + (lane & 7) * 8;
    unsigned short* Asd = &As[wid * 32 * 64];
    unsigned short* Bsd = &Bs[wid * 32 * 64];

    f32x4 acc[4][4];
    #pragma unroll
    for (int i = 0; i < 4; ++i)
        #pragma unroll
        for (int j = 0; j < 4; ++j) acc[i][j] = (f32x4){0.f, 0.f, 0.f, 0.f};

    int nkt = kpart >> 6;
    for (int kt = 0; kt < nkt; ++kt) {
        size_t ko = (size_t)kt << 6;
        #pragma unroll
        for (int q = 0; q < 4; ++q) {
            gload_lds16(Ab + (size_t)(q * 8) * ld + ko, Asd + q * 8 * 64);
            gload_lds16(Bb + (size_t)(q * 8) * ld + ko, Bsd + q * 8 * 64);
        }
        __syncthreads();
        #pragma unroll
        for (int kk = 0; kk < 2; ++kk) {
            bf16x8 af[4], bfr[4];
            #pragma unroll
            for (int m = 0; m < 4; ++m)
                af[m] = *(const bf16x8*)(&As[(wr * 64 + m * 16 + (lane & 15)) * 64 + kk * 32 + (lane >> 4) * 8]);
            #pragma unroll
            for (int n = 0; n < 4; ++n)
                bfr[n] = *(const bf16x8*)(&Bs[(wc * 64 + n * 16 + (lane & 15)) * 64 + kk * 32 + (lane >> 4) * 8]);
            #pragma unroll
            for (int m = 0; m < 4; ++m)
                #pragma unroll
                for (int n = 0; n < 4; ++n)
                    acc[m][n] = __builtin_amdgcn_mfma_f32_16x16x32_bf16(af[m], bfr[n], acc[m][n], 0, 0, 0);
        }
        __syncthreads();
    }

    #pragma unroll
    for (int m = 0; m < 4; ++m) {
        int rbase = row0 + wr * 64 + m * 16 + ((lane >> 4) << 2);
        #pragma unroll
        for (int n = 0; n < 4; ++n) {
            int cg = col0 + wc * 64 + n * 16 + (lane & 15);
            float bv = (MODE == 0) ? bias[cg] : 0.f;
            #pragma unroll
            for (int r2 = 0; r2 < 4; ++r2) {
                float v = acc[m][n][r2];
                int rg = rbase + r2;
                if (MODE == 0) {
                    v += bv;
                    if (DO_ELU) v = v > 0.f ? v : (__expf(v) - 1.f);
                    ((unsigned short*)Out)[(size_t)rg * N + cg] = f2bf(v);
                } else {
                    float* Po = (float*)Out + (size_t)s * 8192 * N;
                    Po[(size_t)rg * N + cg] = v;
                }
            }
        }
    }
}

// ---------------------------------------------------------------------------
// FALLBACK (round-1, known-good, ~60 MB ws): MoE scale folded into staging
// ---------------------------------------------------------------------------
#define LDK 72
template<bool MOE, bool DO_ELU, bool OUT_F32>
__global__ __launch_bounds__(256, 2)
void gemm_v1(const unsigned short* __restrict__ X,
             const unsigned short* __restrict__ WT,
             const float* __restrict__ coeffs,
             const float* __restrict__ bias,
             void* __restrict__ Out,
             int M, int N, int K, int din) {
    __shared__ unsigned short As[128 * LDK];
    __shared__ unsigned short Bs[128 * LDK];
    int nTilesN = N / 128;
    int nwg = gridDim.x;
    int bid = blockIdx.x;
    if ((nwg & 7) == 0) { int cpx = nwg >> 3; bid = (bid & 7) * cpx + (bid >> 3); }
    int tm = bid / nTilesN, tn = bid % nTilesN;
    int row0 = tm * 128, col0 = tn * 128;
    int t = threadIdx.x;
    int lane = t & 63;
    int wid = t >> 6;
    int wr = wid >> 1, wc = wid & 1;
    int srow = t >> 1;
    int sslot = (t & 1) * 4;
    const unsigned short* Xrow = X + (size_t)(row0 + srow) * din;
    const unsigned short* Wrow = WT + (size_t)(col0 + srow) * K;
    f32x4 acc[4][4];
    #pragma unroll
    for (int i = 0; i < 4; ++i)
        #pragma unroll
        for (int j = 0; j < 4; ++j) acc[i][j] = (f32x4){0.f, 0.f, 0.f, 0.f};
    uint4 ra[4], rb[4];
    float scale = 1.0f;
    int nkt = K / 64;
    auto load_tile = [&](int kt) {
        int i0 = kt * 64;
        if (MOE) {
            int e = (kt * 64) / din;
            i0 = kt * 64 - e * din;
            scale = coeffs[(size_t)(row0 + srow) * 8 + e];
        }
        #pragma unroll
        for (int q = 0; q < 4; ++q) {
            ra[q] = *(const uint4*)(Xrow + i0 + (sslot + q) * 8);
            rb[q] = *(const uint4*)(Wrow + kt * 64 + (sslot + q) * 8);
        }
    };
    auto store_tile = [&]() {
        #pragma unroll
        for (int q = 0; q < 4; ++q) {
            uint4 v = ra[q];
            if (MOE) {
                unsigned int w[4] = {v.x, v.y, v.z, v.w};
                #pragma unroll
                for (int p = 0; p < 4; ++p) {
                    float lo = bf2f((unsigned short)(w[p] & 0xFFFFu)) * scale;
                    float hi = bf2f((unsigned short)(w[p] >> 16)) * scale;
                    w[p] = (unsigned int)f2bf(lo) | ((unsigned int)f2bf(hi) << 16);
                }
                v.x = w[0]; v.y = w[1]; v.z = w[2]; v.w = w[3];
            }
            *(uint4*)(&As[srow * LDK + (sslot + q) * 8]) = v;
            *(uint4*)(&Bs[srow * LDK + (sslot + q) * 8]) = rb[q];
        }
    };
    load_tile(0);
    for (int kt = 0; kt < nkt; ++kt) {
        store_tile();
        __syncthreads();
        if (kt + 1 < nkt) load_tile(kt + 1);
        #pragma unroll
        for (int kk = 0; kk < 2; ++kk) {
            bf16x8 af[4], bfr[4];
            #pragma unroll
            for (int m = 0; m < 4; ++m)
                af[m] = *(const bf16x8*)(&As[(wr * 64 + m * 16 + (lane & 15)) * LDK + kk * 32 + (lane >> 4) * 8]);
            #pragma unroll
            for (int n = 0; n < 4; ++n)
                bfr[n] = *(const bf16x8*)(&Bs[(wc * 64 + n * 16 + (lane & 15)) * LDK + kk * 32 + (lane >> 4) * 8]);
            #pragma unroll
            for (int m = 0; m < 4; ++m)
                #pragma unroll
                for (int n = 0; n < 4; ++n)
                    acc[m][n] = __builtin_amdgcn_mfma_f32_16x16x32_bf16(af[m], bfr[n], acc[m][n], 0, 0, 0);
        }
        __syncthreads();
    }
    #pragma unroll
    for (int m = 0; m < 4; ++m) {
        int rbase = row0 + wr * 64 + m * 16 + ((lane >> 4) << 2);
        float crow[4][8];
        if (MOE) {
            #pragma unroll
            for (int r = 0; r < 4; ++r) {
                const float* cp = coeffs + (size_t)(rbase + r) * 8;
                #pragma unroll
                for (int e = 0; e < 8; ++e) crow[r][e] = cp[e];
            }
        }
        #pragma unroll
        for (int n = 0; n < 4; ++n) {
            int cg = col0 + wc * 64 + n * 16 + (lane & 15);
            float bv[8];
            if (MOE) {
                #pragma unroll
                for (int e = 0; e < 8; ++e) bv[e] = bias[(size_t)e * N + cg];
            } else {
                bv[0] = bias[cg];
            }
            #pragma unroll
            for (int r = 0; r < 4; ++r) {
                float v = acc[m][n][r];
                if (MOE) {
                    #pragma unroll
                    for (int e = 0; e < 8; ++e) v += crow[r][e] * bv[e];
                } else {
                    v += bv[0];
                }
                if (DO_ELU) v = v > 0.f ? v : (__expf(v) - 1.f);
                int rg = rbase + r;
                if (OUT_F32) ((float*)Out)[(size_t)rg * N + cg] = v;
                else ((unsigned short*)Out)[(size_t)rg * N + cg] = f2bf(v);
            }
        }
    }
}

// ---------------------------------------------------------------------------
extern "C" void kernel_launch(void* const* d_in, const int* in_sizes, int n_in,
                              void* d_out, int out_size, void* d_ws, size_t ws_size,
                              hipStream_t stream) {
    const float* motion  = (const float*)d_in[0];
    const float* command = (const float*)d_in[1];
    const float* g_w1 = (const float*)d_in[2];
    const float* g_b1 = (const float*)d_in[3];
    const float* g_w2 = (const float*)d_in[4];
    const float* g_b2 = (const float*)d_in[5];
    const float* g_w3 = (const float*)d_in[6];
    const float* g_b3 = (const float*)d_in[7];
    const float* w[6]  = {(const float*)d_in[8],  (const float*)d_in[10],
                          (const float*)d_in[12], (const float*)d_in[14],
                          (const float*)d_in[16], (const float*)d_in[18]};
    const float* bb[6] = {(const float*)d_in[9],  (const float*)d_in[11],
                          (const float*)d_in[13], (const float*)d_in[15],
                          (const float*)d_in[17], (const float*)d_in[19]};

    char* ws = (char*)d_ws;

    if (ws_size >= 261357568ull) {
        // -------- Path A: materialized A' + pure GEMM + split-K --------
        unsigned short* xc0  = (unsigned short*)ws;                       //  9,437,184
        unsigned short* actA = (unsigned short*)(ws + 9437184);           // 16,777,216
        unsigned short* actB = (unsigned short*)(ws + 26214400);          // 16,777,216
        float* coeffs        = (float*)(ws + 42991616);                   //    262,144
        unsigned short* wT   = (unsigned short*)(ws + 43253760);          // 16,777,216
        unsigned short* Aexp = (unsigned short*)(ws + 60030976);          // 134,217,728
        float* part          = (float*)(ws + 194248704);                  // 67,108,864

        concat_cvt<<<4608, 256, 0, stream>>>(motion, command, xc0);

        // gating
        transpose_cvt<<<9 * 16, 256, 0, stream>>>(g_w1, wT, 576, 1024);
        gemm_bf16<0, true><<<512, 256, 0, stream>>>(xc0, wT, g_b1, actA, 1024, 576, 576);
        transpose_cvt<<<16 * 16, 256, 0, stream>>>(g_w2, wT, 1024, 1024);
        gemm_bf16<0, true><<<512, 256, 0, stream>>>(actA, wT, g_b2, actB, 1024, 1024, 1024);
        gating_kernel<<<2048, 256, 0, stream>>>(actB, g_w3, g_b3, coeffs);

        // MoE layer 0: Ktot=4608, splitk=2
        expand_scale<<<18432, 256, 0, stream>>>(xc0, coeffs, Aexp, 576);
        transpose_cvt<<<72 * 16, 256, 0, stream>>>(w[0], wT, 4608, 1024);
        gemm_bf16<1, false><<<1024, 256, 0, stream>>>(Aexp, wT, nullptr, part, 1024, 4608, 2304);
        reduce_bias<2, true, false><<<8192, 256, 0, stream>>>(part, coeffs, bb[0], actA, 1024);

        // MoE layers 1..4: Ktot=8192, splitk=2, ping-pong actA/actB
        unsigned short* bufs[2] = {actA, actB};
        for (int l = 1; l <= 4; ++l) {
            unsigned short* in  = bufs[(l + 1) & 1];
            unsigned short* out = bufs[l & 1];
            expand_scale<<<32768, 256, 0, stream>>>(in, coeffs, Aexp, 1024);
            transpose_cvt<<<128 * 16, 256, 0, stream>>>(w[l], wT, 8192, 1024);
            gemm_bf16<1, false><<<1024, 256, 0, stream>>>(Aexp, wT, nullptr, part, 1024, 8192, 4096);
            reduce_bias<2, true, false><<<8192, 256, 0, stream>>>(part, coeffs, bb[l], out, 1024);
        }

        // MoE layer 5: N=512, splitk=4, fp32 out (L4 output is actA)
        expand_scale<<<32768, 256, 0, stream>>>(actA, coeffs, Aexp, 1024);
        transpose_cvt<<<128 * 8, 256, 0, stream>>>(w[5], wT, 8192, 512);
        gemm_bf16<1, false><<<1024, 256, 0, stream>>>(Aexp, wT, nullptr, part, 512, 8192, 2048);
        reduce_bias<4, false, true><<<4096, 256, 0, stream>>>(part, coeffs, bb[5], d_out, 512);
    } else {
        // -------- Fallback: round-1 path (~60 MB ws) --------
        unsigned short* xc0  = (unsigned short*)ws;
        unsigned short* actA = (unsigned short*)(ws + 9437184);
        unsigned short* actB = (unsigned short*)(ws + 9437184 + 16777216);
        float* coeffs        = (float*)(ws + 9437184 + 2 * 16777216);
        unsigned short* wT   = (unsigned short*)(ws + 9437184 + 2 * 16777216 + 262144);

        concat_cvt<<<4608, 256, 0, stream>>>(motion, command, xc0);
        transpose_cvt<<<9 * 16, 256, 0, stream>>>(g_w1, wT, 576, 1024);
        gemm_v1<false, true, false><<<512, 256, 0, stream>>>(
            xc0, wT, nullptr, g_b1, actA, 8192, 1024, 576, 576);
        transpose_cvt<<<16 * 16, 256, 0, stream>>>(g_w2, wT, 1024, 1024);
        gemm_v1<false, true, false><<<512, 256, 0, stream>>>(
            actA, wT, nullptr, g_b2, actB, 8192, 1024, 1024, 1024);
        gating_kernel<<<2048, 256, 0, stream>>>(actB, g_w3, g_b3, coeffs);
        transpose_cvt<<<72 * 16, 256, 0, stream>>>(w[0], wT, 4608, 1024);
        gemm_v1<true, true, false><<<512, 256, 0, stream>>>(
            xc0, wT, coeffs, bb[0], actA, 8192, 1024, 4608, 576);
        unsigned short* bufs[2] = {actA, actB};
        for (int l = 1; l <= 4; ++l) {
            transpose_cvt<<<128 * 16, 256, 0, stream>>>(w[l], wT, 8192, 1024);
            gemm_v1<true, true, false><<<512, 256, 0, stream>>>(
                bufs[(l + 1) & 1], wT, coeffs, bb[l], bufs[l & 1], 8192, 1024, 8192, 1024);
        }
        transpose_cvt<<<128 * 8, 256, 0, stream>>>(w[5], wT, 8192, 512);
        gemm_v1<true, false, true><<<256, 256, 0, stream>>>(
            actA, wT, coeffs, bb[5], (float*)d_out, 8192, 512, 8192, 1024);
    }
}

// Round 3
// 1121.535 us; speedup vs baseline: 1.8078x; 1.0352x over previous
//
#include <hip/hip_runtime.h>
#include <hip/hip_bf16.h>

typedef __attribute__((ext_vector_type(8))) short bf16x8;
typedef __attribute__((ext_vector_type(4))) float f32x4;

__device__ __forceinline__ float bf2f(unsigned short u) {
    union { unsigned int i; float f; } v; v.i = ((unsigned int)u) << 16; return v.f;
}
__device__ __forceinline__ unsigned short f2bf(float f) {
    union { float f; unsigned int i; } v; v.f = f;
    unsigned int x = v.i;
    return (unsigned short)((x + 0x7FFFu + ((x >> 16) & 1u)) >> 16);
}

__device__ __forceinline__ void gload_lds16(const unsigned short* g, unsigned short* l) {
    __builtin_amdgcn_global_load_lds(
        (const __attribute__((address_space(1))) unsigned int*)g,
        (__attribute__((address_space(3))) unsigned int*)l,
        16, 0, 0);
}

__device__ __forceinline__ uint4 scale_bf16x8(uint4 v, float c) {
    unsigned int w[4] = {v.x, v.y, v.z, v.w};
    #pragma unroll
    for (int p = 0; p < 4; ++p) {
        union { unsigned int i; float f; } lo, hi;
        lo.i = w[p] << 16; hi.i = w[p] & 0xffff0000u;
        float flo = lo.f * c, fhi = hi.f * c;
        w[p] = (unsigned int)f2bf(flo) | ((unsigned int)f2bf(fhi) << 16);
    }
    uint4 o; o.x = w[0]; o.y = w[1]; o.z = w[2]; o.w = w[3];
    return o;
}

#define VM4  asm volatile("s_waitcnt vmcnt(4)" ::: "memory")
#define VM0  asm volatile("s_waitcnt vmcnt(0)" ::: "memory")
#define VM8  asm volatile("s_waitcnt vmcnt(8)" ::: "memory")
#define LG0  asm volatile("s_waitcnt lgkmcnt(0)" ::: "memory")
#define SB0  __builtin_amdgcn_sched_barrier(0)

// ---------------------------------------------------------------------------
// concat(motion, command) -> bf16 [8192, 576]
// ---------------------------------------------------------------------------
__global__ void concat_cvt(const float* __restrict__ motion,
                           const float* __restrict__ command,
                           unsigned short* __restrict__ out) {
    int id = blockIdx.x * 256 + threadIdx.x;
    int b = id / 144, q = id % 144;
    float4 v;
    if (q < 128) v = *(const float4*)(motion + (size_t)b * 512 + q * 4);
    else         v = *(const float4*)(command + (size_t)b * 64 + (q - 128) * 4);
    ushort4 o;
    o.x = f2bf(v.x); o.y = f2bf(v.y); o.z = f2bf(v.z); o.w = f2bf(v.w);
    *(ushort4*)(out + (size_t)b * 576 + q * 4) = o;
}

// ---------------------------------------------------------------------------
// fp32 [K,N] -> bf16 [N,K]
// ---------------------------------------------------------------------------
__global__ void transpose_cvt(const float* __restrict__ in,
                              unsigned short* __restrict__ out,
                              int K, int N) {
    __shared__ unsigned short tile[64][72];
    int nbn = N / 64;
    int k0 = (blockIdx.x / nbn) * 64;
    int n0 = (blockIdx.x % nbn) * 64;
    int t = threadIdx.x;
    int tx = t & 63, ty = t >> 6;
    #pragma unroll
    for (int rr = 0; rr < 16; ++rr) {
        int kr = ty + rr * 4;
        tile[kr][tx] = f2bf(in[(size_t)(k0 + kr) * N + n0 + tx]);
    }
    __syncthreads();
    int txh = t & 31, tyh = t >> 5;
    #pragma unroll
    for (int rr = 0; rr < 8; ++rr) {
        int nr = tyh + rr * 8;
        unsigned int vlo = tile[2 * txh][nr];
        unsigned int vhi = tile[2 * txh + 1][nr];
        unsigned int* o32 = (unsigned int*)(out + (size_t)(n0 + nr) * K + k0);
        o32[txh] = vlo | (vhi << 16);
    }
}

// ---------------------------------------------------------------------------
// gating final: coeffs = softmax(g2 @ w3 + b3)
// ---------------------------------------------------------------------------
__global__ __launch_bounds__(256) void gating_kernel(
    const unsigned short* __restrict__ g2,
    const float* __restrict__ w3, const float* __restrict__ b3,
    float* __restrict__ coeffs) {
    __shared__ float w3s[8][1024];
    int t = threadIdx.x;
    for (int i = t; i < 1024; i += 256) {
        #pragma unroll
        for (int e = 0; e < 8; ++e) w3s[e][i] = w3[(size_t)i * 8 + e];
    }
    __syncthreads();
    int lane = t & 63, wv = t >> 6;
    int row = blockIdx.x * 4 + wv;
    const unsigned short* xr = g2 + (size_t)row * 1024;
    float acc[8];
    #pragma unroll
    for (int e = 0; e < 8; ++e) acc[e] = 0.f;
    for (int it = 0; it < 16; ++it) {
        float xv = bf2f(xr[lane + it * 64]);
        #pragma unroll
        for (int e = 0; e < 8; ++e) acc[e] += xv * w3s[e][lane + it * 64];
    }
    #pragma unroll
    for (int e = 0; e < 8; ++e) {
        float v = acc[e];
        #pragma unroll
        for (int off = 32; off; off >>= 1) v += __shfl_xor(v, off);
        acc[e] = v + b3[e];
    }
    float mx = acc[0];
    #pragma unroll
    for (int e = 1; e < 8; ++e) mx = fmaxf(mx, acc[e]);
    float s = 0.f;
    #pragma unroll
    for (int e = 0; e < 8; ++e) { acc[e] = __expf(acc[e] - mx); s += acc[e]; }
    float inv = 1.f / s;
    if (lane < 8) coeffs[(size_t)row * 8 + lane] = acc[lane] * inv;
}

// ---------------------------------------------------------------------------
// split-K reduce: out = act( sum_s P_s + sum_e c_e * bias_e )
// ---------------------------------------------------------------------------
template<int SPLITS, bool DO_ELU, bool OUT_F32>
__global__ void reduce_bias(const float* __restrict__ P,
                            const float* __restrict__ coeffs,
                            const float* __restrict__ bias,   // [8, N]
                            void* __restrict__ Out, int N) {
    int id = blockIdx.x * 256 + threadIdx.x;
    int nc = N >> 2;
    int b = id / nc, oc = id % nc;
    float4 s = {0.f, 0.f, 0.f, 0.f};
    #pragma unroll
    for (int sp = 0; sp < SPLITS; ++sp) {
        float4 p = *(const float4*)(P + (size_t)sp * 8192 * N + (size_t)b * N + oc * 4);
        s.x += p.x; s.y += p.y; s.z += p.z; s.w += p.w;
    }
    const float* c = coeffs + (size_t)b * 8;
    #pragma unroll
    for (int e = 0; e < 8; ++e) {
        float ce = c[e];
        float4 bv = *(const float4*)(bias + (size_t)e * N + oc * 4);
        s.x += ce * bv.x; s.y += ce * bv.y; s.z += ce * bv.z; s.w += ce * bv.w;
    }
    if (DO_ELU) {
        s.x = s.x > 0.f ? s.x : (__expf(s.x) - 1.f);
        s.y = s.y > 0.f ? s.y : (__expf(s.y) - 1.f);
        s.z = s.z > 0.f ? s.z : (__expf(s.z) - 1.f);
        s.w = s.w > 0.f ? s.w : (__expf(s.w) - 1.f);
    }
    if (OUT_F32) {
        *(float4*)((float*)Out + (size_t)b * N + oc * 4) = s;
    } else {
        ushort4 o;
        o.x = f2bf(s.x); o.y = f2bf(s.y); o.z = f2bf(s.z); o.w = f2bf(s.w);
        *(ushort4*)((unsigned short*)Out + (size_t)b * N + oc * 4) = o;
    }
}

// ---------------------------------------------------------------------------
// gating GEMM (round-2, proven): 128x128x64, global_load_lds both operands
// ---------------------------------------------------------------------------
template<bool DO_ELU>
__global__ __launch_bounds__(256, 4)
void gemm_bf16(const unsigned short* __restrict__ A,
               const unsigned short* __restrict__ BT,
               const float* __restrict__ bias,
               unsigned short* __restrict__ Out,
               int N, int ld, int kpart) {
    __shared__ unsigned short As[128 * 64];
    __shared__ unsigned short Bs[128 * 64];
    int ntn = N >> 7;
    int nwg = gridDim.x;
    int bid = blockIdx.x;
    { int cpx = nwg >> 3; bid = (bid & 7) * cpx + (bid >> 3); }
    int tm = bid / ntn, tn = bid - tm * ntn;
    int row0 = tm << 7, col0 = tn << 7;
    int t = threadIdx.x;
    int lane = t & 63;
    int wid = t >> 6;
    int wr = wid >> 1, wc = wid & 1;
    const unsigned short* Ab = A + (size_t)(row0 + wid * 32 + (lane >> 3)) * ld + (lane & 7) * 8;
    const unsigned short* Bb = BT + (size_t)(col0 + wid * 32 + (lane >> 3)) * ld + (lane & 7) * 8;
    unsigned short* Asd = &As[wid * 32 * 64];
    unsigned short* Bsd = &Bs[wid * 32 * 64];
    f32x4 acc[4][4];
    #pragma unroll
    for (int i = 0; i < 4; ++i)
        #pragma unroll
        for (int j = 0; j < 4; ++j) acc[i][j] = (f32x4){0.f, 0.f, 0.f, 0.f};
    int nkt = kpart >> 6;
    for (int kt = 0; kt < nkt; ++kt) {
        size_t ko = (size_t)kt << 6;
        #pragma unroll
        for (int q = 0; q < 4; ++q) {
            gload_lds16(Ab + (size_t)(q * 8) * ld + ko, Asd + q * 8 * 64);
            gload_lds16(Bb + (size_t)(q * 8) * ld + ko, Bsd + q * 8 * 64);
        }
        __syncthreads();
        #pragma unroll
        for (int kk = 0; kk < 2; ++kk) {
            bf16x8 af[4], bfr[4];
            #pragma unroll
            for (int m = 0; m < 4; ++m)
                af[m] = *(const bf16x8*)(&As[(wr * 64 + m * 16 + (lane & 15)) * 64 + kk * 32 + (lane >> 4) * 8]);
            #pragma unroll
            for (int n = 0; n < 4; ++n)
                bfr[n] = *(const bf16x8*)(&Bs[(wc * 64 + n * 16 + (lane & 15)) * 64 + kk * 32 + (lane >> 4) * 8]);
            #pragma unroll
            for (int m = 0; m < 4; ++m)
                #pragma unroll
                for (int n = 0; n < 4; ++n)
                    acc[m][n] = __builtin_amdgcn_mfma_f32_16x16x32_bf16(af[m], bfr[n], acc[m][n], 0, 0, 0);
        }
        __syncthreads();
    }
    #pragma unroll
    for (int m = 0; m < 4; ++m) {
        int rbase = row0 + wr * 64 + m * 16 + ((lane >> 4) << 2);
        #pragma unroll
        for (int n = 0; n < 4; ++n) {
            int cg = col0 + wc * 64 + n * 16 + (lane & 15);
            float bv = bias[cg];
            #pragma unroll
            for (int r2 = 0; r2 < 4; ++r2) {
                float v = acc[m][n][r2] + bv;
                if (DO_ELU) v = v > 0.f ? v : (__expf(v) - 1.f);
                Out[(size_t)(rbase + r2) * N + cg] = f2bf(v);
            }
        }
    }
}

// ---------------------------------------------------------------------------
// MoE GEMM, deep-pipelined: 256x256 tile, BK=32, ring-3 LDS, counted vmcnt.
// A' scale (coeffs[row, e]) folded into reg-staged A. B via global_load_lds.
// Out: fp32 partial at P + s*8192*N.
// ---------------------------------------------------------------------------
template<int DIN>
__global__ __launch_bounds__(512, 2)
void gemm_moe(const unsigned short* __restrict__ X,   // [8192, DIN] bf16
              const unsigned short* __restrict__ BT,  // [N, 8*DIN]  bf16
              const float* __restrict__ coeffs,       // [8192, 8]
              float* __restrict__ P,
              int N, int kpart, int epart) {          // epart = kpart/DIN
    __shared__ unsigned short lds[49152];             // 3 slots x (A 8192 + B 8192) ushorts
    const int K = DIN * 8;
    int ntn = N >> 8;
    int nwg = gridDim.x;
    int bid = blockIdx.x;
    { int cpx = nwg >> 3; bid = (bid & 7) * cpx + (bid >> 3); }
    int tm = bid & 31;
    int rest = bid >> 5;
    int tn = rest % ntn;
    int s  = rest / ntn;
    int row0 = tm << 8, col0 = tn << 8;
    int k0 = s * kpart;
    int nkt = kpart >> 5;

    int t = threadIdx.x;
    int lane = t & 63, wid = t >> 6;
    int wr = wid >> 2, wc = wid & 3;
    int srow = t >> 2, sslot = t & 3;

    int aoff[8], boff[4];
    #pragma unroll
    for (int f = 0; f < 8; ++f)
        aoff[f] = (wr * 128 + f * 16 + (lane & 15)) * 32 + (lane >> 4) * 8;
    #pragma unroll
    for (int n = 0; n < 4; ++n)
        boff[n] = 8192 + (wc * 64 + n * 16 + (lane & 15)) * 32 + (lane >> 4) * 8;
    int awoff = srow * 32 + sslot * 8;                 // + h*4096 + slot*16384
    int bdoff = 8192 + wid * 512;                      // + h*4096 + slot*16384 (wave-uniform)

    const unsigned short* Abase = X + (size_t)(row0 + srow) * DIN + sslot * 8;
    const unsigned short* Bbase = BT + (size_t)(col0 + wid * 16 + (lane >> 2)) * K + k0 + (lane & 3) * 8;
    const float* Cbase = coeffs + (size_t)(row0 + srow) * 8;

    f32x4 acc[8][4];
    #pragma unroll
    for (int f = 0; f < 8; ++f)
        #pragma unroll
        for (int n = 0; n < 4; ++n) acc[f][n] = (f32x4){0.f, 0.f, 0.f, 0.f};

    uint4 areg0, areg1; float creg0, creg1;
    bf16x8 bfr[4];
    int s0 = 0, s1 = 1, s2 = 2;

    // load-stream state for tile being issued (T+2)
    int le = s * epart;          // expert of tile T+2
    int li0 = 64;                // i0 of tile T+2 (starts at tile 2)
    size_t lkb = 64;             // absolute k offset within [k0, ...) of tile T+2

    // ---- prologue: tiles 0 and 1 ----
    {
        int e0 = s * epart;
        uint4 pa00 = *(const uint4*)(Abase);
        float pc00 = Cbase[e0];
        uint4 pa01 = *(const uint4*)(Abase + (size_t)128 * DIN);
        float pc01 = Cbase[1024 + e0];
        uint4 pa10 = *(const uint4*)(Abase + 32);
        float pc10 = Cbase[e0];
        uint4 pa11 = *(const uint4*)(Abase + (size_t)128 * DIN + 32);
        float pc11 = Cbase[1024 + e0];
        SB0;
        gload_lds16(Bbase,                        &lds[0 * 16384 + bdoff]);
        gload_lds16(Bbase + (size_t)128 * K,      &lds[0 * 16384 + bdoff + 4096]);
        gload_lds16(Bbase + 32,                   &lds[1 * 16384 + bdoff]);
        gload_lds16(Bbase + (size_t)128 * K + 32, &lds[1 * 16384 + bdoff + 4096]);
        VM8; SB0;
        *(uint4*)(&lds[0 * 16384 + awoff])        = scale_bf16x8(pa00, pc00);
        *(uint4*)(&lds[0 * 16384 + 4096 + awoff]) = scale_bf16x8(pa01, pc01);
        VM4; SB0;
        *(uint4*)(&lds[1 * 16384 + awoff])        = scale_bf16x8(pa10, pc10);
        *(uint4*)(&lds[1 * 16384 + 4096 + awoff]) = scale_bf16x8(pa11, pc11);
        VM0; LG0;
        __builtin_amdgcn_s_barrier();
        SB0;
    }

    for (int T = 0; T < nkt; ++T) {
        const bool do_wb = (T >= 1) && (T <= nkt - 2);
        const bool do_ld = (T <= nkt - 3);

        // ======== phase 0 ========
        if (do_wb) {
            VM4; SB0;
            *(uint4*)(&lds[s1 * 16384 + awoff]) = scale_bf16x8(areg0, creg0);
        }
        {
            int sb = s0 * 16384;
            #pragma unroll
            for (int n = 0; n < 4; ++n)
                bfr[n] = *(const bf16x8*)(&lds[sb + boff[n]]);
        }
        bf16x8 af0_0 = *(const bf16x8*)(&lds[s0 * 16384 + aoff[0]]);
        bf16x8 af0_1 = *(const bf16x8*)(&lds[s0 * 16384 + aoff[1]]);
        bf16x8 af0_2 = *(const bf16x8*)(&lds[s0 * 16384 + aoff[2]]);
        bf16x8 af0_3 = *(const bf16x8*)(&lds[s0 * 16384 + aoff[3]]);
        if (do_ld) {
            areg0 = *(const uint4*)(Abase + (size_t)li0);
            creg0 = Cbase[le];
            SB0;
            gload_lds16(Bbase + lkb,                   &lds[s2 * 16384 + bdoff]);
            gload_lds16(Bbase + (size_t)128 * K + lkb, &lds[s2 * 16384 + bdoff + 4096]);
        }
        __builtin_amdgcn_s_barrier();
        LG0; SB0;
        __builtin_amdgcn_s_setprio(1);
        #pragma unroll
        for (int n = 0; n < 4; ++n) {
            acc[0][n] = __builtin_amdgcn_mfma_f32_16x16x32_bf16(af0_0, bfr[n], acc[0][n], 0, 0, 0);
            acc[1][n] = __builtin_amdgcn_mfma_f32_16x16x32_bf16(af0_1, bfr[n], acc[1][n], 0, 0, 0);
            acc[2][n] = __builtin_amdgcn_mfma_f32_16x16x32_bf16(af0_2, bfr[n], acc[2][n], 0, 0, 0);
            acc[3][n] = __builtin_amdgcn_mfma_f32_16x16x32_bf16(af0_3, bfr[n], acc[3][n], 0, 0, 0);
        }
        __builtin_amdgcn_s_setprio(0);
        __builtin_amdgcn_s_barrier();
        SB0;

        // ======== phase 1 ========
        if (do_wb) {
            if (T == nkt - 2) { VM0; } else { VM4; }
            SB0;
            *(uint4*)(&lds[s1 * 16384 + 4096 + awoff]) = scale_bf16x8(areg1, creg1);
        }
        bf16x8 af1_0 = *(const bf16x8*)(&lds[s0 * 16384 + aoff[4]]);
        bf16x8 af1_1 = *(const bf16x8*)(&lds[s0 * 16384 + aoff[5]]);
        bf16x8 af1_2 = *(const bf16x8*)(&lds[s0 * 16384 + aoff[6]]);
        bf16x8 af1_3 = *(const bf16x8*)(&lds[s0 * 16384 + aoff[7]]);
        if (do_ld) {
            areg1 = *(const uint4*)(Abase + (size_t)128 * DIN + li0);
            creg1 = Cbase[1024 + le];
        }
        __builtin_amdgcn_s_barrier();
        LG0; SB0;
        __builtin_amdgcn_s_setprio(1);
        #pragma unroll
        for (int n = 0; n < 4; ++n) {
            acc[4][n] = __builtin_amdgcn_mfma_f32_16x16x32_bf16(af1_0, bfr[n], acc[4][n], 0, 0, 0);
            acc[5][n] = __builtin_amdgcn_mfma_f32_16x16x32_bf16(af1_1, bfr[n], acc[5][n], 0, 0, 0);
            acc[6][n] = __builtin_amdgcn_mfma_f32_16x16x32_bf16(af1_2, bfr[n], acc[6][n], 0, 0, 0);
            acc[7][n] = __builtin_amdgcn_mfma_f32_16x16x32_bf16(af1_3, bfr[n], acc[7][n], 0, 0, 0);
        }
        __builtin_amdgcn_s_setprio(0);
        __builtin_amdgcn_s_barrier();
        SB0;

        // rotate ring slots, advance load stream
        int tmp = s0; s0 = s1; s1 = s2; s2 = tmp;
        li0 += 32; lkb += 32;
        if (li0 == DIN) { li0 = 0; le += 1; }
    }

    // epilogue: fp32 partial
    float* Po = P + (size_t)s * 8192 * N;
    #pragma unroll
    for (int f = 0; f < 8; ++f) {
        int rg = row0 + wr * 128 + f * 16 + ((lane >> 4) << 2);
        #pragma unroll
        for (int n = 0; n < 4; ++n) {
            int cg = col0 + wc * 64 + n * 16 + (lane & 15);
            #pragma unroll
            for (int r = 0; r < 4; ++r)
                Po[(size_t)(rg + r) * N + cg] = acc[f][n][r];
        }
    }
}

// ---------------------------------------------------------------------------
extern "C" void kernel_launch(void* const* d_in, const int* in_sizes, int n_in,
                              void* d_out, int out_size, void* d_ws, size_t ws_size,
                              hipStream_t stream) {
    const float* motion  = (const float*)d_in[0];
    const float* command = (const float*)d_in[1];
    const float* g_w1 = (const float*)d_in[2];
    const float* g_b1 = (const float*)d_in[3];
    const float* g_w2 = (const float*)d_in[4];
    const float* g_b2 = (const float*)d_in[5];
    const float* g_w3 = (const float*)d_in[6];
    const float* g_b3 = (const float*)d_in[7];
    const float* w[6]  = {(const float*)d_in[8],  (const float*)d_in[10],
                          (const float*)d_in[12], (const float*)d_in[14],
                          (const float*)d_in[16], (const float*)d_in[18]};
    const float* bb[6] = {(const float*)d_in[9],  (const float*)d_in[11],
                          (const float*)d_in[13], (const float*)d_in[15],
                          (const float*)d_in[17], (const float*)d_in[19]};

    char* ws = (char*)d_ws;
    unsigned short* xc0  = (unsigned short*)ws;                 //  9,437,184
    unsigned short* actA = (unsigned short*)(ws + 9437184);     // 16,777,216
    unsigned short* actB = (unsigned short*)(ws + 26214400);    // 16,777,216
    float* coeffs        = (float*)(ws + 42991616);             //    262,144
    unsigned short* wT   = (unsigned short*)(ws + 43253760);    // 16,777,216
    float* part          = (float*)(ws + 60030976);             // 67,108,864

    // 1. concat + convert input
    concat_cvt<<<4608, 256, 0, stream>>>(motion, command, xc0);

    // 2. gating network
    transpose_cvt<<<9 * 16, 256, 0, stream>>>(g_w1, wT, 576, 1024);
    gemm_bf16<true><<<512, 256, 0, stream>>>(xc0, wT, g_b1, actA, 1024, 576, 576);
    transpose_cvt<<<16 * 16, 256, 0, stream>>>(g_w2, wT, 1024, 1024);
    gemm_bf16<true><<<512, 256, 0, stream>>>(actA, wT, g_b2, actB, 1024, 1024, 1024);
    gating_kernel<<<2048, 256, 0, stream>>>(actB, g_w3, g_b3, coeffs);

    // 3. MoE layer 0: K=4608, DIN=576, split-K=2 (kpart=2304, epart=4)
    transpose_cvt<<<72 * 16, 256, 0, stream>>>(w[0], wT, 4608, 1024);
    gemm_moe<576><<<256, 512, 0, stream>>>(xc0, wT, coeffs, part, 1024, 2304, 4);
    reduce_bias<2, true, false><<<8192, 256, 0, stream>>>(part, coeffs, bb[0], actA, 1024);

    // 4. MoE layers 1..4: K=8192, DIN=1024, split-K=2 (kpart=4096, epart=4)
    unsigned short* bufs[2] = {actA, actB};
    for (int l = 1; l <= 4; ++l) {
        unsigned short* in  = bufs[(l + 1) & 1];
        unsigned short* out = bufs[l & 1];
        transpose_cvt<<<128 * 16, 256, 0, stream>>>(w[l], wT, 8192, 1024);
        gemm_moe<1024><<<256, 512, 0, stream>>>(in, wT, coeffs, part, 1024, 4096, 4);
        reduce_bias<2, true, false><<<8192, 256, 0, stream>>>(part, coeffs, bb[l], out, 1024);
    }

    // 5. MoE layer 5: N=512, split-K=4 (kpart=2048, epart=2), fp32 out
    transpose_cvt<<<128 * 8, 256, 0, stream>>>(w[5], wT, 8192, 512);
    gemm_moe<1024><<<256, 512, 0, stream>>>(actA, wT, coeffs, part, 512, 2048, 2);
    reduce_bias<4, false, true><<<4096, 256, 0, stream>>>(part, coeffs, bb[5], d_out, 512);
}

// Round 4
// 1018.049 us; speedup vs baseline: 1.9916x; 1.1017x over previous
//
#include <hip/hip_runtime.h>
#include <hip/hip_bf16.h>

typedef __attribute__((ext_vector_type(8))) short bf16x8;
typedef __attribute__((ext_vector_type(4))) float f32x4;

__device__ __forceinline__ float bf2f(unsigned short u) {
    union { unsigned int i; float f; } v; v.i = ((unsigned int)u) << 16; return v.f;
}
__device__ __forceinline__ unsigned short f2bf(float f) {
    union { float f; unsigned int i; } v; v.f = f;
    unsigned int x = v.i;
    return (unsigned short)((x + 0x7FFFu + ((x >> 16) & 1u)) >> 16);
}

__device__ __forceinline__ void gload_lds16(const unsigned short* g, unsigned short* l) {
    __builtin_amdgcn_global_load_lds(
        (const __attribute__((address_space(1))) unsigned int*)g,
        (__attribute__((address_space(3))) unsigned int*)l,
        16, 0, 0);
}

#define VM4  asm volatile("s_waitcnt vmcnt(4)" ::: "memory")
#define VM0  asm volatile("s_waitcnt vmcnt(0)" ::: "memory")
#define LG0  asm volatile("s_waitcnt lgkmcnt(0)" ::: "memory")
#define SB0  __builtin_amdgcn_sched_barrier(0)

// ---------------------------------------------------------------------------
// concat(motion, command) -> bf16 [8192, 576]
// ---------------------------------------------------------------------------
__global__ void concat_cvt(const float* __restrict__ motion,
                           const float* __restrict__ command,
                           unsigned short* __restrict__ out) {
    int id = blockIdx.x * 256 + threadIdx.x;
    int b = id / 144, q = id % 144;
    float4 v;
    if (q < 128) v = *(const float4*)(motion + (size_t)b * 512 + q * 4);
    else         v = *(const float4*)(command + (size_t)b * 64 + (q - 128) * 4);
    ushort4 o;
    o.x = f2bf(v.x); o.y = f2bf(v.y); o.z = f2bf(v.z); o.w = f2bf(v.w);
    *(ushort4*)(out + (size_t)b * 576 + q * 4) = o;
}

// ---------------------------------------------------------------------------
// batched fp32 [K,N] -> bf16 [N,K] per expert (tpe = 64x64 tiles per expert)
// ---------------------------------------------------------------------------
__global__ void transpose_cvt(const float* __restrict__ in,
                              unsigned short* __restrict__ out,
                              int K, int N, int tpe) {
    __shared__ unsigned short tile[64][72];
    int e = blockIdx.x / tpe, r = blockIdx.x % tpe;
    in  += (size_t)e * K * N;
    out += (size_t)e * N * K;
    int nbn = N / 64;
    int k0 = (r / nbn) * 64;
    int n0 = (r % nbn) * 64;
    int t = threadIdx.x;
    int tx = t & 63, ty = t >> 6;
    #pragma unroll
    for (int rr = 0; rr < 16; ++rr) {
        int kr = ty + rr * 4;
        tile[kr][tx] = f2bf(in[(size_t)(k0 + kr) * N + n0 + tx]);
    }
    __syncthreads();
    int txh = t & 31, tyh = t >> 5;
    #pragma unroll
    for (int rr = 0; rr < 8; ++rr) {
        int nr = tyh + rr * 8;
        unsigned int vlo = tile[2 * txh][nr];
        unsigned int vhi = tile[2 * txh + 1][nr];
        unsigned int* o32 = (unsigned int*)(out + (size_t)(n0 + nr) * K + k0);
        o32[txh] = vlo | (vhi << 16);
    }
}

// ---------------------------------------------------------------------------
// gating final: coeffs = softmax(g2 @ w3 + b3)
// ---------------------------------------------------------------------------
__global__ __launch_bounds__(256) void gating_kernel(
    const unsigned short* __restrict__ g2,
    const float* __restrict__ w3, const float* __restrict__ b3,
    float* __restrict__ coeffs) {
    __shared__ float w3s[8][1024];
    int t = threadIdx.x;
    for (int i = t; i < 1024; i += 256) {
        #pragma unroll
        for (int e = 0; e < 8; ++e) w3s[e][i] = w3[(size_t)i * 8 + e];
    }
    __syncthreads();
    int lane = t & 63, wv = t >> 6;
    int row = blockIdx.x * 4 + wv;
    const unsigned short* xr = g2 + (size_t)row * 1024;
    float acc[8];
    #pragma unroll
    for (int e = 0; e < 8; ++e) acc[e] = 0.f;
    for (int it = 0; it < 16; ++it) {
        float xv = bf2f(xr[lane + it * 64]);
        #pragma unroll
        for (int e = 0; e < 8; ++e) acc[e] += xv * w3s[e][lane + it * 64];
    }
    #pragma unroll
    for (int e = 0; e < 8; ++e) {
        float v = acc[e];
        #pragma unroll
        for (int off = 32; off; off >>= 1) v += __shfl_xor(v, off);
        acc[e] = v + b3[e];
    }
    float mx = acc[0];
    #pragma unroll
    for (int e = 1; e < 8; ++e) mx = fmaxf(mx, acc[e]);
    float s = 0.f;
    #pragma unroll
    for (int e = 0; e < 8; ++e) { acc[e] = __expf(acc[e] - mx); s += acc[e]; }
    float inv = 1.f / s;
    if (lane < 8) coeffs[(size_t)row * 8 + lane] = acc[lane] * inv;
}

// ---------------------------------------------------------------------------
// reduce: out[b,o] = act( sum_e c[b,e] * (Z[b, e*dout+o] + bias[e*dout+o]) )
// ---------------------------------------------------------------------------
template<bool DO_ELU, bool OUT_F32>
__global__ void reduce_moe(const unsigned short* __restrict__ Z,  // [8192, 8*dout]
                           const float* __restrict__ coeffs,
                           const float* __restrict__ bias,        // [8*dout]
                           void* __restrict__ Out, int dout) {
    int id = blockIdx.x * 256 + threadIdx.x;
    int nc = dout >> 3;
    int b = id / nc, j = id - b * nc;
    int o0 = j << 3;
    const unsigned short* zr = Z + ((size_t)b * dout << 3);
    const float* cp = coeffs + (size_t)b * 8;
    float acc[8];
    #pragma unroll
    for (int k = 0; k < 8; ++k) acc[k] = 0.f;
    #pragma unroll
    for (int e = 0; e < 8; ++e) {
        float c = cp[e];
        const unsigned short* zp = zr + e * dout + o0;
        ushort4 z0 = *(const ushort4*)(zp);
        ushort4 z1 = *(const ushort4*)(zp + 4);
        const float* bp = bias + e * dout + o0;
        float4 b0 = *(const float4*)(bp);
        float4 b1 = *(const float4*)(bp + 4);
        acc[0] += c * (bf2f(z0.x) + b0.x);
        acc[1] += c * (bf2f(z0.y) + b0.y);
        acc[2] += c * (bf2f(z0.z) + b0.z);
        acc[3] += c * (bf2f(z0.w) + b0.w);
        acc[4] += c * (bf2f(z1.x) + b1.x);
        acc[5] += c * (bf2f(z1.y) + b1.y);
        acc[6] += c * (bf2f(z1.z) + b1.z);
        acc[7] += c * (bf2f(z1.w) + b1.w);
    }
    if (DO_ELU) {
        #pragma unroll
        for (int k = 0; k < 8; ++k) acc[k] = acc[k] > 0.f ? acc[k] : (__expf(acc[k]) - 1.f);
    }
    if (OUT_F32) {
        float* op = (float*)Out + (size_t)b * dout + o0;
        float4 v0 = {acc[0], acc[1], acc[2], acc[3]};
        float4 v1 = {acc[4], acc[5], acc[6], acc[7]};
        *(float4*)(op) = v0; *(float4*)(op + 4) = v1;
    } else {
        unsigned short* op = (unsigned short*)Out + (size_t)b * dout + o0;
        ushort4 v0, v1;
        v0.x = f2bf(acc[0]); v0.y = f2bf(acc[1]); v0.z = f2bf(acc[2]); v0.w = f2bf(acc[3]);
        v1.x = f2bf(acc[4]); v1.y = f2bf(acc[5]); v1.z = f2bf(acc[6]); v1.w = f2bf(acc[7]);
        *(ushort4*)(op) = v0; *(ushort4*)(op + 4) = v1;
    }
}

// ---------------------------------------------------------------------------
// 8-phase 256x256 pure bf16 GEMM. BK=32 slots, 4-slot LDS ring (128 KB),
// both operands via global_load_lds with inverse-swizzled source, swizzled
// ds_read (slot' = slot ^ ((row>>1)&3) within 64B rows -> 2-way, free).
// Counted vmcnt(4), 2 barriers/phase, setprio around MFMA.
// EPI 0: raw bf16 store (Z). EPI 1: bias+ELU bf16 store (gating).
// ---------------------------------------------------------------------------
template<int EPI>
__global__ __launch_bounds__(512, 2)
void gemm8p(const unsigned short* __restrict__ A,   // [8192, K]
            const unsigned short* __restrict__ BT,  // [N, K]
            const float* __restrict__ bias,         // [N] (EPI 1)
            unsigned short* __restrict__ Out,       // [8192, N]
            int N, int K) {
    __shared__ unsigned short lds[65536];           // 4 x (A 8192 + B 8192)

    int ntn = N >> 8;
    int nwg = gridDim.x;
    int bid = blockIdx.x;
    { int cpx = nwg >> 3; bid = (bid & 7) * cpx + (bid >> 3); }
    int tm = bid / ntn, tn = bid - tm * ntn;
    int row0 = tm << 8, col0 = tn << 8;
    int nkt = K >> 5;                                // 32-wide K slots

    int t = threadIdx.x;
    int lane = t & 63, wid = t >> 6;
    int wm = wid >> 2, wn = wid & 3;                 // 2x4 waves, each 128x64
    int q = lane >> 4;

    // fragment ds_read offsets (ushort units), swizzled
    int aoff[8], boff[4];
    #pragma unroll
    for (int m = 0; m < 8; ++m) {
        int row = wm * 128 + m * 16 + (lane & 15);
        aoff[m] = row * 32 + ((q ^ ((row >> 1) & 3)) << 3);
    }
    #pragma unroll
    for (int n = 0; n < 4; ++n) {
        int row = wn * 64 + n * 16 + (lane & 15);
        boff[n] = 8192 + row * 32 + ((q ^ ((row >> 1) & 3)) << 3);
    }

    // stage source (per-thread, inverse-swizzled column)
    int srow = t >> 2;
    int scol = ((t & 3) ^ ((t >> 3) & 3)) * 8;
    const unsigned short* Asrc = A + (size_t)(row0 + srow) * K + scol;
    const unsigned short* Bsrc = BT + (size_t)(col0 + srow) * K + scol;
    int wdst = wid * 512;                            // wave-uniform dest term

    f32x4 acc[8][4];
    #pragma unroll
    for (int m = 0; m < 8; ++m)
        #pragma unroll
        for (int n = 0; n < 4; ++n) acc[m][n] = (f32x4){0.f, 0.f, 0.f, 0.f};

    // ---- prologue: stage slots 0, 1 ----
    #pragma unroll
    for (int S = 0; S < 2; ++S) {
        gload_lds16(Asrc + S * 32,                    &lds[S * 16384 + wdst]);
        gload_lds16(Asrc + (size_t)128 * K + S * 32,  &lds[S * 16384 + 4096 + wdst]);
        gload_lds16(Bsrc + S * 32,                    &lds[S * 16384 + 8192 + wdst]);
        gload_lds16(Bsrc + (size_t)128 * K + S * 32,  &lds[S * 16384 + 12288 + wdst]);
    }
    VM4; SB0;
    __builtin_amdgcn_s_barrier();

    for (int s = 0; s < nkt; ++s) {
        int sb = (s & 3) << 14;
        bool st = (s + 2) < nkt;
        int rb2 = ((s + 2) & 3) << 14;
        int ko2 = (s + 2) * 32;

        // ======== phase A: B-frags + A m0-3, stage A(s+2) ========
        bf16x8 bfrg[4], afr[4];
        #pragma unroll
        for (int n = 0; n < 4; ++n)
            bfrg[n] = *(const bf16x8*)(&lds[sb + boff[n]]);
        #pragma unroll
        for (int m = 0; m < 4; ++m)
            afr[m] = *(const bf16x8*)(&lds[sb + aoff[m]]);
        if (st) {
            gload_lds16(Asrc + ko2,                   &lds[rb2 + wdst]);
            gload_lds16(Asrc + (size_t)128 * K + ko2, &lds[rb2 + 4096 + wdst]);
        }
        SB0;
        __builtin_amdgcn_s_barrier();
        LG0; SB0;
        __builtin_amdgcn_s_setprio(1);
        #pragma unroll
        for (int m = 0; m < 4; ++m)
            #pragma unroll
            for (int n = 0; n < 4; ++n)
                acc[m][n] = __builtin_amdgcn_mfma_f32_16x16x32_bf16(afr[m], bfrg[n], acc[m][n], 0, 0, 0);
        __builtin_amdgcn_s_setprio(0);
        __builtin_amdgcn_s_barrier();

        // ======== phase B: A m4-7, stage B(s+2), vmcnt ========
        bf16x8 afr2[4];
        #pragma unroll
        for (int m = 0; m < 4; ++m)
            afr2[m] = *(const bf16x8*)(&lds[sb + aoff[m + 4]]);
        if (st) {
            gload_lds16(Bsrc + ko2,                   &lds[rb2 + 8192 + wdst]);
            gload_lds16(Bsrc + (size_t)128 * K + ko2, &lds[rb2 + 12288 + wdst]);
        }
        SB0;
        if (s + 1 < nkt) {
            if (st) { VM4; } else { VM0; }
        }
        SB0;
        __builtin_amdgcn_s_barrier();
        LG0; SB0;
        __builtin_amdgcn_s_setprio(1);
        #pragma unroll
        for (int m = 0; m < 4; ++m)
            #pragma unroll
            for (int n = 0; n < 4; ++n)
                acc[m + 4][n] = __builtin_amdgcn_mfma_f32_16x16x32_bf16(afr2[m], bfrg[n], acc[m + 4][n], 0, 0, 0);
        __builtin_amdgcn_s_setprio(0);
        __builtin_amdgcn_s_barrier();
    }

    // epilogue
    #pragma unroll
    for (int m = 0; m < 8; ++m) {
        int rg = row0 + wm * 128 + m * 16 + ((lane >> 4) << 2);
        #pragma unroll
        for (int n = 0; n < 4; ++n) {
            int cg = col0 + wn * 64 + n * 16 + (lane & 15);
            float bv = (EPI == 1) ? bias[cg] : 0.f;
            #pragma unroll
            for (int r = 0; r < 4; ++r) {
                float v = acc[m][n][r];
                if (EPI == 1) {
                    v += bv;
                    v = v > 0.f ? v : (__expf(v) - 1.f);
                }
                Out[(size_t)(rg + r) * N + cg] = f2bf(v);
            }
        }
    }
}

// ---------------------------------------------------------------------------
extern "C" void kernel_launch(void* const* d_in, const int* in_sizes, int n_in,
                              void* d_out, int out_size, void* d_ws, size_t ws_size,
                              hipStream_t stream) {
    const float* motion  = (const float*)d_in[0];
    const float* command = (const float*)d_in[1];
    const float* g_w1 = (const float*)d_in[2];
    const float* g_b1 = (const float*)d_in[3];
    const float* g_w2 = (const float*)d_in[4];
    const float* g_b2 = (const float*)d_in[5];
    const float* g_w3 = (const float*)d_in[6];
    const float* g_b3 = (const float*)d_in[7];
    const float* w[6]  = {(const float*)d_in[8],  (const float*)d_in[10],
                          (const float*)d_in[12], (const float*)d_in[14],
                          (const float*)d_in[16], (const float*)d_in[18]};
    const float* bb[6] = {(const float*)d_in[9],  (const float*)d_in[11],
                          (const float*)d_in[13], (const float*)d_in[15],
                          (const float*)d_in[17], (const float*)d_in[19]};

    char* ws = (char*)d_ws;
    unsigned short* xc0  = (unsigned short*)ws;                 //  9,437,184
    unsigned short* actA = (unsigned short*)(ws + 9437184);     // 16,777,216
    unsigned short* actB = (unsigned short*)(ws + 26214400);    // 16,777,216
    float* coeffs        = (float*)(ws + 42991616);             //    262,144
    unsigned short* wT   = (unsigned short*)(ws + 43253760);    // 16,777,216
    unsigned short* Z    = (unsigned short*)(ws + 60030976);    // 134,217,728

    // 1. concat + convert input
    concat_cvt<<<4608, 256, 0, stream>>>(motion, command, xc0);

    // 2. gating network
    transpose_cvt<<<144, 256, 0, stream>>>(g_w1, wT, 576, 1024, 144);
    gemm8p<1><<<128, 512, 0, stream>>>(xc0, wT, g_b1, actA, 1024, 576);
    transpose_cvt<<<256, 256, 0, stream>>>(g_w2, wT, 1024, 1024, 256);
    gemm8p<1><<<128, 512, 0, stream>>>(actA, wT, g_b2, actB, 1024, 1024);
    gating_kernel<<<2048, 256, 0, stream>>>(actB, g_w3, g_b3, coeffs);

    // 3. MoE layer 0: Z = xc0 @ W0 (all experts), N = 8192, K = 576
    transpose_cvt<<<1152, 256, 0, stream>>>(w[0], wT, 576, 1024, 144);
    gemm8p<0><<<1024, 512, 0, stream>>>(xc0, wT, nullptr, Z, 8192, 576);
    reduce_moe<true, false><<<4096, 256, 0, stream>>>(Z, coeffs, bb[0], actA, 1024);

    // 4. MoE layers 1..4: N = 8192, K = 1024
    unsigned short* bufs[2] = {actA, actB};
    for (int l = 1; l <= 4; ++l) {
        unsigned short* in  = bufs[(l + 1) & 1];
        unsigned short* out = bufs[l & 1];
        transpose_cvt<<<2048, 256, 0, stream>>>(w[l], wT, 1024, 1024, 256);
        gemm8p<0><<<1024, 512, 0, stream>>>(in, wT, nullptr, Z, 8192, 1024);
        reduce_moe<true, false><<<4096, 256, 0, stream>>>(Z, coeffs, bb[l], out, 1024);
    }

    // 5. MoE layer 5: N = 8*512 = 4096, K = 1024, fp32 out
    transpose_cvt<<<1024, 256, 0, stream>>>(w[5], wT, 1024, 512, 128);
    gemm8p<0><<<512, 512, 0, stream>>>(actA, wT, nullptr, Z, 4096, 1024);
    reduce_moe<false, true><<<2048, 256, 0, stream>>>(Z, coeffs, bb[5], d_out, 512);
}